// Round 11
// baseline (262.657 us; speedup 1.0000x reference)
//
#include <hip/hip_runtime.h>

#define N_ 16384
#define D_ 256
#define LOG2E 1.4426950408889634f
#define HEXP2(x) __builtin_amdgcn_exp2f(x)

typedef __attribute__((ext_vector_type(8))) short short8;
typedef __attribute__((ext_vector_type(16))) float floatx16;

typedef __attribute__((address_space(1))) const unsigned int gu32_t;
typedef __attribute__((address_space(3))) unsigned int lu32_t;

__device__ __forceinline__ void async16(const void* g, void* l) {
  __builtin_amdgcn_global_load_lds((gu32_t*)g, (lu32_t*)l, 16, 0, 0);
}

__device__ __forceinline__ unsigned short f2bf(float x) {
  unsigned int u = __float_as_uint(x);
  u += 0x7fffu + ((u >> 16) & 1u);
  return (unsigned short)(u >> 16);
}

// ---------------- prep: fp32 -> bf16 packed (write-coalesced) + fused exact diag ----------------
// (passed rounds 1, 2, 5, 8, 10)
__global__ void prep_pack(const float* __restrict__ img, const float* __restrict__ txt,
                          const float* __restrict__ ls, short* __restrict__ PA,
                          short* __restrict__ PB, float* __restrict__ diag2,
                          float* __restrict__ out) {
  const int tid = threadIdx.x;
  const int t = blockIdx.x * 1024 + tid;
  const int m = tid & 31, h = (tid >> 5) & 1, ks = (tid >> 6) & 15;
  const int G = blockIdx.x;
  const int row = G * 32 + m, col = ks * 16 + h * 8;
  const float s2 = ls[0] * LOG2E;
  const float4* sa = (const float4*)(img + (size_t)row * D_ + col);
  const float4* sb = (const float4*)(txt + (size_t)row * D_ + col);
  float4 a0 = sa[0], a1 = sa[1];
  float4 b0 = sb[0], b1 = sb[1];
  short8 oa, ob;
  oa[0] = (short)f2bf(a0.x * s2); oa[1] = (short)f2bf(a0.y * s2);
  oa[2] = (short)f2bf(a0.z * s2); oa[3] = (short)f2bf(a0.w * s2);
  oa[4] = (short)f2bf(a1.x * s2); oa[5] = (short)f2bf(a1.y * s2);
  oa[6] = (short)f2bf(a1.z * s2); oa[7] = (short)f2bf(a1.w * s2);
  ob[0] = (short)f2bf(b0.x); ob[1] = (short)f2bf(b0.y);
  ob[2] = (short)f2bf(b0.z); ob[3] = (short)f2bf(b0.w);
  ob[4] = (short)f2bf(b1.x); ob[5] = (short)f2bf(b1.y);
  ob[6] = (short)f2bf(b1.z); ob[7] = (short)f2bf(b1.w);
  ((short8*)PA)[t] = oa;
  ((short8*)PB)[t] = ob;

  float d = a0.x * b0.x + a0.y * b0.y + a0.z * b0.z + a0.w * b0.w
          + a1.x * b1.x + a1.y * b1.y + a1.z * b1.z + a1.w * b1.w;
  __shared__ float red[32][33];
  red[tid >> 5][m] = d;
  __syncthreads();
  if (tid < 32) {
    float s = 0.f;
    #pragma unroll
    for (int q = 0; q < 32; ++q) s += red[q][tid];
    diag2[G * 32 + tid] = s * s2;  // log2-domain scaled diagonal
  }
  if (t == 0) out[0] = 0.f;
}

// ---------------- gemm + stats: 32x128 wave tiles -> 3 blocks/CU ----------------
// Same staging/vmcnt/phase-barrier discipline as the green r5/r8 kernel; wave tile
// changed 64x64 -> 32x128 (r1-proven geometry) so areg drops 128->64 VGPR and the
// kernel fits __launch_bounds__(256,3): 3 blocks/CU (was register-pinned at 2).
// Stats (all r1-proven pieces, serialized):
//  * wave-uniform msub (tree max + 6-step butterfly), exp2 in place
//  * col partials: each wave covers ALL 128 cols over its 32 rows ->
//    colbuf[4][128] + one seal barrier + tid<128 LSE-merge of the 4 partials
//  * rows fully wave-owned -> wave-private LDS transpose (rbw, lgkm fence only,
//    NO barrier), Mr/Sr in registers, single pR write at kernel end
//  * no closing barrier (r10-proven subsumption: next colbuf write is behind
//    the next tile's 8 phase barriers)
// LDS 54272 B (32KB staging + 17KB rbw + 4KB colbuf); x3 = 162816 <= 163840.
// BANNED (r2/r3/r4/r6/r7/r9): setprio; 4-buffer single-barrier staging; racc row
// path + end transpose; colbuf double-buffer; per-wave-private staging; XCD
// swizzle; launch_bounds(256,3) WITH the 64x64 tile (spills: r9).
__global__ __launch_bounds__(256, 3)
void gemm_stats(const short* __restrict__ PA, const short* __restrict__ PB,
                float2* __restrict__ pR, float2* __restrict__ pC) {
  __shared__ __align__(16) char smem[54272];
  // [0,32768): B staging dbuf (2 x 16KB, frag (colgrp g, ks-slice s) at g*4096+s*1024)
  // [32768,50176): rbw per-wave scratch: w*4352, f32 [32 rows][stride 34]
  // [50176,54272): colbuf float2[4 waves][128 cols]
  float2* colbuf = (float2*)(smem + 50176);

  const int tid = threadIdx.x, lane = tid & 63, w = tid >> 6;
  const int m = lane & 31, h = lane >> 5;
  const int stripe = blockIdx.x, by = blockIdx.y;
  float* rbw = (float*)(smem + 32768 + w * 4352);

  // ---- A panel into registers: rows stripe*128 + w*32 .. +32, all K (64 VGPR)
  short8 areg[16];
  #pragma unroll
  for (int ks = 0; ks < 16; ++ks)
    areg[ks] = *(const short8*)(PA + ((size_t)((stripe * 4 + w) * 16 + ks)) * 512 + lane * 8);
  asm volatile("s_waitcnt vmcnt(0)" ::: "memory");

  floatx16 acc[4];

  // stage chunk (jj2, c2) -> buffer bufsel; wave w stages ks-slice w for 4 colgrp frags
  // (byte-identical to the green r5 discipline)
  auto issue = [&](int jj2, int c2, int bufsel) {
    const short* base = PB + ((size_t)((by * 64 + jj2 * 4) * 16) + c2 * 4 + w) * 512 + lane * 8;
    char* dst = smem + bufsel * 16384 + w * 1024;
    #pragma unroll
    for (int ct = 0; ct < 4; ++ct)
      async16(base + (size_t)ct * 8192, dst + ct * 4096);
  };
  auto compute = [&](int c, int bufsel) {
    char* base = smem + bufsel * 16384 + lane * 16;
    #pragma unroll
    for (int ksl = 0; ksl < 4; ++ksl) {
      short8 b0 = *(const short8*)(base + 0 * 4096 + ksl * 1024);
      short8 b1 = *(const short8*)(base + 1 * 4096 + ksl * 1024);
      short8 b2 = *(const short8*)(base + 2 * 4096 + ksl * 1024);
      short8 b3 = *(const short8*)(base + 3 * 4096 + ksl * 1024);
      int ks = c * 4 + ksl;  // compile-time under unroll
      acc[0] = __builtin_amdgcn_mfma_f32_32x32x16_bf16(areg[ks], b0, acc[0], 0, 0, 0);
      acc[1] = __builtin_amdgcn_mfma_f32_32x32x16_bf16(areg[ks], b1, acc[1], 0, 0, 0);
      acc[2] = __builtin_amdgcn_mfma_f32_32x32x16_bf16(areg[ks], b2, acc[2], 0, 0, 0);
      acc[3] = __builtin_amdgcn_mfma_f32_32x32x16_bf16(areg[ks], b3, acc[3], 0, 0, 0);
    }
  };

  issue(0, 0, 0);
  issue(0, 1, 1);

  float Mr = -3.0e38f, Sr = 0.f;  // row LSE state: row = stripe*128 + w*32 + m

  #pragma unroll 1
  for (int jj = 0; jj < 16; ++jj) {
    #pragma unroll
    for (int g = 0; g < 4; ++g)
      #pragma unroll
      for (int r = 0; r < 16; ++r) acc[g][r] = 0.f;

    #pragma unroll
    for (int c = 0; c < 4; ++c) {
      if (jj == 15 && c == 3) { asm volatile("s_waitcnt vmcnt(0)" ::: "memory"); }
      else                    { asm volatile("s_waitcnt vmcnt(4)" ::: "memory"); }
      __builtin_amdgcn_s_barrier();
      asm volatile("" ::: "memory");
      compute(c, c & 1);
      asm volatile("" ::: "memory");
      __builtin_amdgcn_s_barrier();
      asm volatile("" ::: "memory");
      int nc = c + 2;
      int jj2 = jj + (nc >> 2);
      if (jj2 < 16) issue(jj2, nc & 3, nc & 1);
    }

    // ---- stats. acc[g][r]: row(in wave tile) = (r&3)+8*(r>>2)+4*h, col = g*32+m
    float vm[4];
    #pragma unroll
    for (int g = 0; g < 4; ++g) {
      float a01 = fmaxf(acc[g][0],  acc[g][1]);
      float a23 = fmaxf(acc[g][2],  acc[g][3]);
      float a45 = fmaxf(acc[g][4],  acc[g][5]);
      float a67 = fmaxf(acc[g][6],  acc[g][7]);
      float a89 = fmaxf(acc[g][8],  acc[g][9]);
      float aab = fmaxf(acc[g][10], acc[g][11]);
      float acd = fmaxf(acc[g][12], acc[g][13]);
      float aef = fmaxf(acc[g][14], acc[g][15]);
      vm[g] = fmaxf(fmaxf(fmaxf(a01, a23), fmaxf(a45, a67)),
                    fmaxf(fmaxf(a89, aab), fmaxf(acd, aef)));
    }
    float v = fmaxf(fmaxf(vm[0], vm[1]), fmaxf(vm[2], vm[3]));
    #pragma unroll
    for (int off = 1; off < 64; off <<= 1) v = fmaxf(v, __shfl_xor(v, off));
    float msub = v - 96.f;

    #pragma unroll
    for (int g = 0; g < 4; ++g)
      #pragma unroll
      for (int r = 0; r < 16; ++r) acc[g][r] = HEXP2(acc[g][r] - msub);

    // col partials: sum over this wave's 32 rows (16 reg-local + xor32 for other half)
    #pragma unroll
    for (int g = 0; g < 4; ++g) {
      float cp = ((acc[g][0]  + acc[g][1])  + (acc[g][2]  + acc[g][3]))
               + ((acc[g][4]  + acc[g][5])  + (acc[g][6]  + acc[g][7]))
               + ((acc[g][8]  + acc[g][9])  + (acc[g][10] + acc[g][11]))
               + ((acc[g][12] + acc[g][13]) + (acc[g][14] + acc[g][15]));
      cp += __shfl_xor(cp, 32);
      if (h == 0) colbuf[w * 128 + g * 32 + m] = make_float2(msub, cp);
    }

    // row partials: g-sum -> wave-private transpose rbw[row][m] (no barrier)
    #pragma unroll
    for (int r = 0; r < 16; ++r) {
      float x = (acc[0][r] + acc[1][r]) + (acc[2][r] + acc[3][r]);
      rbw[((r & 3) + 8 * (r >> 2) + 4 * h) * 34 + m] = x;
    }
    asm volatile("s_waitcnt lgkmcnt(0)" ::: "memory");
    // lane reads its row m: 16 of 32 entries (h split), then xor32 for the rest
    {
      const float2* rb2 = (const float2*)(rbw + m * 34 + h * 16);
      float s = 0.f;
      #pragma unroll
      for (int j = 0; j < 8; ++j) { float2 q = rb2[j]; s += q.x + q.y; }
      s += __shfl_xor(s, 32);
      if (s > 0.f) {
        if (msub > Mr) { Sr = Sr * HEXP2(Mr - msub) + s; Mr = msub; }
        else           { Sr += s * HEXP2(msub - Mr); }
      }
    }

    // seal colbuf, then merge the 4 wave partials -> pC
    asm volatile("s_waitcnt lgkmcnt(0)" ::: "memory");
    __builtin_amdgcn_s_barrier();
    asm volatile("" ::: "memory");
    if (tid < 128) {
      float M = -3.0e38f, L = 0.f;
      #pragma unroll
      for (int s4 = 0; s4 < 4; ++s4) {
        float2 pp = colbuf[s4 * 128 + tid];
        if (pp.y > 0.f) {
          if (pp.x > M) { L = L * HEXP2(M - pp.x) + pp.y; M = pp.x; }
          else          { L += pp.y * HEXP2(pp.x - M); }
        }
      }
      pC[(size_t)stripe * N_ + by * 2048 + jj * 128 + tid] = make_float2(M, L);
    }
    // (no closing barrier: next colbuf write is behind jj+1's 8 phase barriers)
  }

  if (h == 0)
    pR[(size_t)by * N_ + stripe * 128 + w * 32 + m] = make_float2(Mr, Sr);
}

// ---------------- merge v2: parallelized (passed rounds 8, 10) ----------------
__global__ void merge_kernel(const float2* __restrict__ pR, const float2* __restrict__ pC,
                             const float* __restrict__ diag2, float* __restrict__ out) {
  auto mrg = [](float& M, float& L, float2 w) {
    if (w.y > 0.f) {
      if (w.x > M) { L = L * exp2f(M - w.x) + w.y; M = w.x; }
      else         { L += w.y * exp2f(w.x - M); }
    }
  };
  const int b = blockIdx.x, tid = threadIdx.x;
  float val = 0.f;

  if (b < 64) {
    int i = b * 256 + tid;
    float M = -3.0e38f, L = 0.f;
    #pragma unroll
    for (int g = 0; g < 8; ++g) mrg(M, L, pR[(size_t)g * N_ + i]);
    val = (M + log2f(fmaxf(L, 1e-45f))) - diag2[i];
  } else {
    int cb = b - 64;                 // 0..511
    int i = cb * 32 + (tid & 31);
    int s0 = (tid >> 5) * 16;
    float M = -3.0e38f, L = 0.f;
    #pragma unroll
    for (int k = 0; k < 16; ++k) mrg(M, L, pC[(size_t)(s0 + k) * N_ + i]);
    __shared__ float2 part[8][32];
    part[tid >> 5][tid & 31] = make_float2(M, L);
    __syncthreads();
    if (tid < 32) {
      float M2 = -3.0e38f, L2 = 0.f;
      #pragma unroll
      for (int q = 0; q < 8; ++q) mrg(M2, L2, part[q][tid]);
      val = (M2 + log2f(fmaxf(L2, 1e-45f))) - diag2[cb * 32 + tid];
    }
  }

  __shared__ float red[256];
  red[tid] = val;
  __syncthreads();
  #pragma unroll
  for (int s = 128; s > 0; s >>= 1) {
    if (tid < s) red[tid] += red[tid + s];
    __syncthreads();
  }
  if (tid == 0)
    atomicAdd(out, red[0] * (0.69314718055994531f / 32768.0f));  // ln2 / (2N)
}

// ---------------- launch ----------------
extern "C" void kernel_launch(void* const* d_in, const int* in_sizes, int n_in,
                              void* d_out, int out_size, void* d_ws, size_t ws_size,
                              hipStream_t stream) {
  const float* img = (const float*)d_in[0];
  const float* txt = (const float*)d_in[1];
  const float* ls  = (const float*)d_in[2];
  float* out = (float*)d_out;

  char* ws = (char*)d_ws;
  short* PA    = (short*)(ws);                 //  8 MB
  short* PB    = (short*)(ws + 8388608);       //  8 MB
  float* diag2 = (float*)(ws + 16777216);      //  64 KB
  float2* pR   = (float2*)(ws + 16843008);     //  1 MB  (8 x N)
  float2* pC   = (float2*)(ws + 17891584);     //  16 MB (128 x N)

  hipLaunchKernelGGL(prep_pack, dim3(512), dim3(1024), 0, stream, img, txt, ls, PA, PB, diag2, out);
  hipLaunchKernelGGL(gemm_stats, dim3(128, 8), dim3(256), 0, stream, PA, PB, pR, pC);
  hipLaunchKernelGGL(merge_kernel, dim3(576), dim3(256), 0, stream, pR, pC, diag2, out);
}

// Round 12
// 240.811 us; speedup vs baseline: 1.0907x; 1.0907x over previous
//
#include <hip/hip_runtime.h>

#define N_ 16384
#define D_ 256
#define LOG2E 1.4426950408889634f
#define HEXP2(x) __builtin_amdgcn_exp2f(x)

typedef __attribute__((ext_vector_type(8))) short short8;
typedef __attribute__((ext_vector_type(16))) float floatx16;

typedef __attribute__((address_space(1))) const unsigned int gu32_t;
typedef __attribute__((address_space(3))) unsigned int lu32_t;

__device__ __forceinline__ void async16(const void* g, void* l) {
  __builtin_amdgcn_global_load_lds((gu32_t*)g, (lu32_t*)l, 16, 0, 0);
}

__device__ __forceinline__ unsigned short f2bf(float x) {
  unsigned int u = __float_as_uint(x);
  u += 0x7fffu + ((u >> 16) & 1u);
  return (unsigned short)(u >> 16);
}

__device__ __forceinline__ float max3f(float a, float b, float c) {
  return fmaxf(fmaxf(a, b), c);  // clang folds to v_max3_f32
}

// ---------------- prep: fp32 -> bf16 packed (write-coalesced) + fused exact diag ----------------
// (passed rounds 1, 2, 5, 8, 10)
__global__ void prep_pack(const float* __restrict__ img, const float* __restrict__ txt,
                          const float* __restrict__ ls, short* __restrict__ PA,
                          short* __restrict__ PB, float* __restrict__ diag2,
                          float* __restrict__ out) {
  const int tid = threadIdx.x;
  const int t = blockIdx.x * 1024 + tid;
  const int m = tid & 31, h = (tid >> 5) & 1, ks = (tid >> 6) & 15;
  const int G = blockIdx.x;
  const int row = G * 32 + m, col = ks * 16 + h * 8;
  const float s2 = ls[0] * LOG2E;
  const float4* sa = (const float4*)(img + (size_t)row * D_ + col);
  const float4* sb = (const float4*)(txt + (size_t)row * D_ + col);
  float4 a0 = sa[0], a1 = sa[1];
  float4 b0 = sb[0], b1 = sb[1];
  short8 oa, ob;
  oa[0] = (short)f2bf(a0.x * s2); oa[1] = (short)f2bf(a0.y * s2);
  oa[2] = (short)f2bf(a0.z * s2); oa[3] = (short)f2bf(a0.w * s2);
  oa[4] = (short)f2bf(a1.x * s2); oa[5] = (short)f2bf(a1.y * s2);
  oa[6] = (short)f2bf(a1.z * s2); oa[7] = (short)f2bf(a1.w * s2);
  ob[0] = (short)f2bf(b0.x); ob[1] = (short)f2bf(b0.y);
  ob[2] = (short)f2bf(b0.z); ob[3] = (short)f2bf(b0.w);
  ob[4] = (short)f2bf(b1.x); ob[5] = (short)f2bf(b1.y);
  ob[6] = (short)f2bf(b1.z); ob[7] = (short)f2bf(b1.w);
  ((short8*)PA)[t] = oa;
  ((short8*)PB)[t] = ob;

  float d = a0.x * b0.x + a0.y * b0.y + a0.z * b0.z + a0.w * b0.w
          + a1.x * b1.x + a1.y * b1.y + a1.z * b1.z + a1.w * b1.w;
  __shared__ float red[32][33];
  red[tid >> 5][m] = d;
  __syncthreads();
  if (tid < 32) {
    float s = 0.f;
    #pragma unroll
    for (int q = 0; q < 32; ++q) s += red[q][tid];
    diag2[G * 32 + tid] = s * s2;  // log2-domain scaled diagonal
  }
  if (t == 0) out[0] = 0.f;
}

// ---------------- gemm + stats: A-in-registers, continuous B pipeline ----------------
// r8 structure (best green: gemm 170us) with register-local micro-opts only:
//  * acc zero-init deleted: first MFMA of each tile takes a persistent zero vector
//    as C (D = A*B + 0 writes acc fresh; D != C is legal) -- 64 fewer v_mov/tile.
//  * max3-shaped max tree (v_max3_f32 folding) -- shorter reduce, fewer ops.
//  * 4-chain row sum in phase2 (was a 32-deep dependent add chain).
//  * r10-proven closing-barrier removal (9 barriers/tile).
// GEOMETRY FIXED: 64x64 wave tiles (ds_read:MFMA=0.5). 32x128 regresses (r1, r11:
// 2x ds_read, no occupancy gain -- 3rd block never co-schedules: LDS granularity).
// OCCUPANCY PINNED at 2 blocks/CU (r9: launch_bounds(256,3) spills, FETCH 412MB).
// BANNED (r2/r3/r4/r6/r7/r9/r11): setprio; 4-buffer single-barrier staging; racc
// row path + end transpose; colbuf double-buffer; per-wave-private staging; XCD
// swizzle; 3 waves/EU; 32x128 tiles.
__global__ __launch_bounds__(256, 2)
void gemm_stats(const short* __restrict__ PA, const short* __restrict__ PB,
                float2* __restrict__ pR, float2* __restrict__ pC) {
  __shared__ __align__(16) char smem[73728];
  // [0,32768): B staging dbuf (2 x 16KB, 16 frags x 1KB each)
  // [32768,71680): rowbuf f32 [wr*64+slot][76] (38912 B)
  // [71680,73728): colbuf float2[2][128]
  float* rowbuf  = (float*)(smem + 32768);
  float2* colbuf = (float2*)(smem + 71680);

  const int tid = threadIdx.x, lane = tid & 63, wv = tid >> 6;
  const int wr = wv >> 1, wc = wv & 1;
  const int m = lane & 31, h = lane >> 5;
  const int stripe = blockIdx.x, by = blockIdx.y;

  // ---- A panel into registers: rows stripe*128 + wr*64 .. +64, all K
  short8 areg[2][16];
  #pragma unroll
  for (int g = 0; g < 2; ++g)
    #pragma unroll
    for (int ks = 0; ks < 16; ++ks)
      areg[g][ks] = *(const short8*)(PA +
          ((size_t)((stripe * 4 + wr * 2 + g) * 16 + ks)) * 512 + lane * 8);
  asm volatile("s_waitcnt vmcnt(0)" ::: "memory");

  floatx16 acc[2][2];
  floatx16 zv;
  #pragma unroll
  for (int r = 0; r < 16; ++r) zv[r] = 0.f;

  // stage chunk (jj2, c2) -> buffer bufsel. Wave wv stages ks-slice wv for 4 ct frags.
  auto issue = [&](int jj2, int c2, int bufsel) {
    const short* base = PB + ((size_t)((by * 64 + jj2 * 4) * 16) + c2 * 4 + wv) * 512 + lane * 8;
    char* dst = smem + bufsel * 16384 + wv * 1024;
    #pragma unroll
    for (int ct = 0; ct < 4; ++ct)
      async16(base + (size_t)ct * 8192, dst + ct * 4096);
  };
  auto compute = [&](int c, int bufsel, bool first) {
    char* base = smem + bufsel * 16384 + lane * 16;
    #pragma unroll
    for (int ksl = 0; ksl < 4; ++ksl) {
      short8 b0 = *(const short8*)(base + ((wc * 2 + 0) * 4 + ksl) * 1024);
      short8 b1 = *(const short8*)(base + ((wc * 2 + 1) * 4 + ksl) * 1024);
      int ks = c * 4 + ksl;  // compile-time under unroll
      if (first && ksl == 0) {
        acc[0][0] = __builtin_amdgcn_mfma_f32_32x32x16_bf16(areg[0][ks], b0, zv, 0, 0, 0);
        acc[1][0] = __builtin_amdgcn_mfma_f32_32x32x16_bf16(areg[1][ks], b0, zv, 0, 0, 0);
        acc[0][1] = __builtin_amdgcn_mfma_f32_32x32x16_bf16(areg[0][ks], b1, zv, 0, 0, 0);
        acc[1][1] = __builtin_amdgcn_mfma_f32_32x32x16_bf16(areg[1][ks], b1, zv, 0, 0, 0);
      } else {
        acc[0][0] = __builtin_amdgcn_mfma_f32_32x32x16_bf16(areg[0][ks], b0, acc[0][0], 0, 0, 0);
        acc[1][0] = __builtin_amdgcn_mfma_f32_32x32x16_bf16(areg[1][ks], b0, acc[1][0], 0, 0, 0);
        acc[0][1] = __builtin_amdgcn_mfma_f32_32x32x16_bf16(areg[0][ks], b1, acc[0][1], 0, 0, 0);
        acc[1][1] = __builtin_amdgcn_mfma_f32_32x32x16_bf16(areg[1][ks], b1, acc[1][1], 0, 0, 0);
      }
    }
  };

  issue(0, 0, 0);
  issue(0, 1, 1);

  float Mr = -3.0e38f, Sr = 0.f;  // row LSE state: row = stripe*128 + wr*64 + wc*32 + m

  for (int jj = 0; jj < 16; ++jj) {
    #pragma unroll
    for (int c = 0; c < 4; ++c) {
      if (jj == 15 && c == 3) { asm volatile("s_waitcnt vmcnt(0)" ::: "memory"); }
      else                    { asm volatile("s_waitcnt vmcnt(4)" ::: "memory"); }
      __builtin_amdgcn_s_barrier();
      asm volatile("" ::: "memory");
      compute(c, c & 1, c == 0);
      asm volatile("" ::: "memory");
      __builtin_amdgcn_s_barrier();
      asm volatile("" ::: "memory");
      int nc = c + 2;
      int jj2 = jj + (nc >> 2);
      if (jj2 < 16) issue(jj2, nc & 3, nc & 1);
    }

    // ---- stats. acc[rt][ctl][reg]: row(in tile) = wr*64+rt*32+(reg&3)+8*(reg>>2)+4*h
    //                                col(in tile) = wc*64+ctl*32+m
    // max3-shaped reduce (v_max3_f32): 16 values -> 8 ops, short chains
    float vm[4];
    #pragma unroll
    for (int q = 0; q < 4; ++q) {
      const floatx16& a = acc[q >> 1][q & 1];
      float t0 = max3f(a[0],  a[1],  a[2]);
      float t1 = max3f(a[3],  a[4],  a[5]);
      float t2 = max3f(a[6],  a[7],  a[8]);
      float t3 = max3f(a[9],  a[10], a[11]);
      float t4 = max3f(a[12], a[13], a[14]);
      vm[q] = fmaxf(max3f(t0, t1, a[15]), max3f(t2, t3, t4));
    }
    float v = fmaxf(max3f(vm[0], vm[1], vm[2]), vm[3]);
    #pragma unroll
    for (int off = 1; off < 64; off <<= 1) v = fmaxf(v, __shfl_xor(v, off));
    float msub = v - 96.f;

    #pragma unroll
    for (int rt = 0; rt < 2; ++rt)
      #pragma unroll
      for (int ctl = 0; ctl < 2; ++ctl)
        #pragma unroll
        for (int r = 0; r < 16; ++r) acc[rt][ctl][r] = HEXP2(acc[rt][ctl][r] - msub);

    // col partials: sum over 64 rows of wave tile (reg-local + xor32)
    #pragma unroll
    for (int ctl = 0; ctl < 2; ++ctl) {
      float cp0 = 0.f, cp1 = 0.f;
      #pragma unroll
      for (int r = 0; r < 8; ++r) {
        cp0 += acc[0][ctl][r] + acc[1][ctl][r];
        cp1 += acc[0][ctl][r + 8] + acc[1][ctl][r + 8];
      }
      float cp = cp0 + cp1;
      cp += __shfl_xor(cp, 32);
      if (h == 0) colbuf[wr * 128 + wc * 64 + ctl * 32 + m] = make_float2(msub, cp);
    }

    // row partials: ctl-add, pack 4 rows -> float4, rowbuf[(wr*64+slot)*76 + row]
    #pragma unroll
    for (int rt = 0; rt < 2; ++rt)
      #pragma unroll
      for (int rq = 0; rq < 4; ++rq) {
        float4 rp;
        rp.x = acc[rt][0][rq * 4 + 0] + acc[rt][1][rq * 4 + 0];
        rp.y = acc[rt][0][rq * 4 + 1] + acc[rt][1][rq * 4 + 1];
        rp.z = acc[rt][0][rq * 4 + 2] + acc[rt][1][rq * 4 + 2];
        rp.w = acc[rt][0][rq * 4 + 3] + acc[rt][1][rq * 4 + 3];
        *(float4*)&rowbuf[(wr * 64 + wc * 32 + m) * 76 + rt * 32 + rq * 8 + h * 4] = rp;
      }
    asm volatile("s_waitcnt lgkmcnt(0)" ::: "memory");
    __builtin_amdgcn_s_barrier();
    asm volatile("" ::: "memory");

    // phase2 rows: 4 parallel chains (was one 32-deep dependent chain)
    {
      float s0 = 0.f, s1 = 0.f, s2 = 0.f, s3 = 0.f;
      #pragma unroll
      for (int k = 0; k < 8; ++k) {
        s0 += rowbuf[(wr * 64 + h * 32 + k)      * 76 + wc * 32 + m];
        s1 += rowbuf[(wr * 64 + h * 32 + k + 8)  * 76 + wc * 32 + m];
        s2 += rowbuf[(wr * 64 + h * 32 + k + 16) * 76 + wc * 32 + m];
        s3 += rowbuf[(wr * 64 + h * 32 + k + 24) * 76 + wc * 32 + m];
      }
      float s = (s0 + s1) + (s2 + s3);
      s += __shfl_xor(s, 32);
      if (s > 0.f) {
        if (msub > Mr) { Sr = Sr * HEXP2(Mr - msub) + s; Mr = msub; }
        else           { Sr += s * HEXP2(msub - Mr); }
      }
    }
    // phase2 cols: merge wr=0/1 partials -> pC
    if (tid < 128) {
      float2 c0 = colbuf[tid], c1 = colbuf[128 + tid];
      float M = -3.0e38f, L = 0.f;
      if (c0.y > 0.f) { M = c0.x; L = c0.y; }
      if (c1.y > 0.f) {
        if (c1.x > M) { L = L * HEXP2(M - c1.x) + c1.y; M = c1.x; }
        else          { L += c1.y * HEXP2(c1.x - M); }
      }
      pC[(size_t)stripe * N_ + by * 2048 + jj * 128 + tid] = make_float2(M, L);
    }
    // (closing barrier removed -- r10-proven: next rowbuf/colbuf write is behind
    //  tile jj+1's 8 phase barriers)
  }

  if (h == 0)
    pR[(size_t)by * N_ + stripe * 128 + wr * 64 + wc * 32 + m] = make_float2(Mr, Sr);
}

// ---------------- merge v2: parallelized (passed rounds 8, 10) ----------------
__global__ void merge_kernel(const float2* __restrict__ pR, const float2* __restrict__ pC,
                             const float* __restrict__ diag2, float* __restrict__ out) {
  auto mrg = [](float& M, float& L, float2 w) {
    if (w.y > 0.f) {
      if (w.x > M) { L = L * exp2f(M - w.x) + w.y; M = w.x; }
      else         { L += w.y * exp2f(w.x - M); }
    }
  };
  const int b = blockIdx.x, tid = threadIdx.x;
  float val = 0.f;

  if (b < 64) {
    int i = b * 256 + tid;
    float M = -3.0e38f, L = 0.f;
    #pragma unroll
    for (int g = 0; g < 8; ++g) mrg(M, L, pR[(size_t)g * N_ + i]);
    val = (M + log2f(fmaxf(L, 1e-45f))) - diag2[i];
  } else {
    int cb = b - 64;                 // 0..511
    int i = cb * 32 + (tid & 31);
    int s0 = (tid >> 5) * 16;
    float M = -3.0e38f, L = 0.f;
    #pragma unroll
    for (int k = 0; k < 16; ++k) mrg(M, L, pC[(size_t)(s0 + k) * N_ + i]);
    __shared__ float2 part[8][32];
    part[tid >> 5][tid & 31] = make_float2(M, L);
    __syncthreads();
    if (tid < 32) {
      float M2 = -3.0e38f, L2 = 0.f;
      #pragma unroll
      for (int q = 0; q < 8; ++q) mrg(M2, L2, part[q][tid]);
      val = (M2 + log2f(fmaxf(L2, 1e-45f))) - diag2[cb * 32 + tid];
    }
  }

  __shared__ float red[256];
  red[tid] = val;
  __syncthreads();
  #pragma unroll
  for (int s = 128; s > 0; s >>= 1) {
    if (tid < s) red[tid] += red[tid + s];
    __syncthreads();
  }
  if (tid == 0)
    atomicAdd(out, red[0] * (0.69314718055994531f / 32768.0f));  // ln2 / (2N)
}

// ---------------- launch ----------------
extern "C" void kernel_launch(void* const* d_in, const int* in_sizes, int n_in,
                              void* d_out, int out_size, void* d_ws, size_t ws_size,
                              hipStream_t stream) {
  const float* img = (const float*)d_in[0];
  const float* txt = (const float*)d_in[1];
  const float* ls  = (const float*)d_in[2];
  float* out = (float*)d_out;

  char* ws = (char*)d_ws;
  short* PA    = (short*)(ws);                 //  8 MB
  short* PB    = (short*)(ws + 8388608);       //  8 MB
  float* diag2 = (float*)(ws + 16777216);      //  64 KB
  float2* pR   = (float2*)(ws + 16843008);     //  1 MB  (8 x N)
  float2* pC   = (float2*)(ws + 17891584);     //  16 MB (128 x N)

  hipLaunchKernelGGL(prep_pack, dim3(512), dim3(1024), 0, stream, img, txt, ls, PA, PB, diag2, out);
  hipLaunchKernelGGL(gemm_stats, dim3(128, 8), dim3(256), 0, stream, PA, PB, pR, pC);
  hipLaunchKernelGGL(merge_kernel, dim3(576), dim3(256), 0, stream, pR, pC, diag2, out);
}